// Round 5
// baseline (731.382 us; speedup 1.0000x reference)
//
#include <hip/hip_runtime.h>
#include <hip/hip_bf16.h>

// Problem constants
#define HIDDEN   4096
#define N_HEADS  32
#define N_KV     8
#define N_REP    4
#define HEAD_DIM 128
#define CACHE    4096
#define BATCH    32

#define PJ_THREADS 128
#define PJ_COLS    256     // columns per block (2 per thread)
#define PJ_HCHUNK  128     // K-chunk per block (grid.y = 4096/128 = 32)

typedef float f4v __attribute__((ext_vector_type(4)));

// ---------------------------------------------------------------------------
// Skinny GEMM: part[hc][b][col] = sum_{h in chunk} X[b][h] * W[h][col], M=32.
// (unchanged from round 2/3/4)
// ---------------------------------------------------------------------------
__global__ __launch_bounds__(128) void proj_kernel(
    const float* __restrict__ X,           // [32][4096]
    const float* __restrict__ W1, int ld1, int ncol1,
    const float* __restrict__ W2, int ld2,
    float* __restrict__ part, int ncols)
{
    __shared__ float xs[32 * PJ_HCHUNK];   // 16 KB
    const int hc   = blockIdx.y;           // 0..31
    const int h0   = hc * PJ_HCHUNK;
    const int col0 = blockIdx.x * PJ_COLS;
    const int tid  = threadIdx.x;

    for (int i = tid * 4; i < 32 * PJ_HCHUNK; i += PJ_THREADS * 4) {
        int b = i >> 7, j = i & 127;
        *(float4*)&xs[i] = *(const float4*)&X[(size_t)b * HIDDEN + h0 + j];
    }
    __syncthreads();

    const int col = col0 + tid * 2;
    const float* Wp;
    size_t ld;
    if (col < ncol1) { Wp = W1 + (size_t)h0 * ld1 + col;           ld = ld1; }
    else             { Wp = W2 + (size_t)h0 * ld2 + (col - ncol1); ld = ld2; }

    float2 acc[32];
#pragma unroll
    for (int b = 0; b < 32; ++b) acc[b] = make_float2(0.f, 0.f);

    float2 wc0 = *(const float2*)(Wp);
    float2 wc1 = *(const float2*)(Wp + ld);
    float2 wc2 = *(const float2*)(Wp + 2 * ld);
    float2 wc3 = *(const float2*)(Wp + 3 * ld);

    for (int hh = 0; hh < PJ_HCHUNK; hh += 4) {
        const float* Wn = Wp + 4 * ld;
        float2 wn0, wn1, wn2, wn3;
        if (hh < PJ_HCHUNK - 4) {
            wn0 = *(const float2*)(Wn);
            wn1 = *(const float2*)(Wn + ld);
            wn2 = *(const float2*)(Wn + 2 * ld);
            wn3 = *(const float2*)(Wn + 3 * ld);
        }
        const float* xr = xs + hh;
#pragma unroll
        for (int b = 0; b < 32; ++b) {
            float4 xv = *(const float4*)(xr + b * PJ_HCHUNK);
            acc[b].x = fmaf(xv.x, wc0.x, acc[b].x);
            acc[b].y = fmaf(xv.x, wc0.y, acc[b].y);
            acc[b].x = fmaf(xv.y, wc1.x, acc[b].x);
            acc[b].y = fmaf(xv.y, wc1.y, acc[b].y);
            acc[b].x = fmaf(xv.z, wc2.x, acc[b].x);
            acc[b].y = fmaf(xv.z, wc2.y, acc[b].y);
            acc[b].x = fmaf(xv.w, wc3.x, acc[b].x);
            acc[b].y = fmaf(xv.w, wc3.y, acc[b].y);
        }
        wc0 = wn0; wc1 = wn1; wc2 = wn2; wc3 = wn3;
        Wp = Wn;
    }

    float* dst = part + ((size_t)hc * 32) * ncols + col;
#pragma unroll
    for (int b = 0; b < 32; ++b)
        *(float2*)(dst + (size_t)b * ncols) = acc[b];
}

// Sum 32 h-chunk partials. grid = (ncols/256, 32)
__global__ __launch_bounds__(256) void combine_proj(
    const float* __restrict__ part, int ncols,
    float* __restrict__ dst1, int ld1, int ncol1,
    float* __restrict__ dst2, int ld2)
{
    const int col = blockIdx.x * 256 + threadIdx.x;
    const int b   = blockIdx.y;
    float s = 0.f;
#pragma unroll
    for (int i = 0; i < 32; ++i) s += part[((size_t)i * 32 + b) * ncols + col];
    if (col < ncol1) dst1[(size_t)b * ld1 + col] = s;
    else             dst2[(size_t)b * ld2 + (col - ncol1)] = s;
}

// ---------------------------------------------------------------------------
// Decode attention — identical to round 4 (measurement round: launched 3x).
// ---------------------------------------------------------------------------

#define DOT8(PART, QA, QB)                         \
    PART = QA.x * ka.x;                            \
    PART = fmaf(QA.y, ka.y, PART);                 \
    PART = fmaf(QA.z, ka.z, PART);                 \
    PART = fmaf(QA.w, ka.w, PART);                 \
    PART = fmaf(QB.x, kb4.x, PART);                \
    PART = fmaf(QB.y, kb4.y, PART);                \
    PART = fmaf(QB.z, kb4.z, PART);                \
    PART = fmaf(QB.w, kb4.w, PART);

#define RED4(M)                                    \
    part0 += __shfl_xor(part0, M, 64);             \
    part1 += __shfl_xor(part1, M, 64);             \
    part2 += __shfl_xor(part2, M, 64);             \
    part3 += __shfl_xor(part3, M, 64);

#define PVROW(PR, OA, OB)                          \
    OA.x = fmaf(PR, va.x,  OA.x);                  \
    OA.y = fmaf(PR, va.y,  OA.y);                  \
    OA.z = fmaf(PR, va.z,  OA.z);                  \
    OA.w = fmaf(PR, va.w,  OA.w);                  \
    OB.x = fmaf(PR, vb4.x, OB.x);                  \
    OB.y = fmaf(PR, vb4.y, OB.y);                  \
    OB.z = fmaf(PR, vb4.z, OB.z);                  \
    OB.w = fmaf(PR, vb4.w, OB.w);

#define REDV(V, M)                                 \
    V.x += __shfl_xor(V.x, M, 64);                 \
    V.y += __shfl_xor(V.y, M, 64);                 \
    V.z += __shfl_xor(V.z, M, 64);                 \
    V.w += __shfl_xor(V.w, M, 64);

__global__ __launch_bounds__(256, 4) void attn_kernel(
    const float* __restrict__ q,      // [32][4096], col = (kv*4+r)*128+d
    const float* __restrict__ kc,     // [32][8][4096][128]
    const float* __restrict__ vc,
    float* __restrict__ po,
    float* __restrict__ pl)
{
    const int bid   = blockIdx.x;      // 0..2047
    const int pair  = bid >> 3;        // 0..255
    const int sg    = bid & 7;
    const int tid   = threadIdx.x;
    const int w     = tid >> 6;
    const int lane  = tid & 63;
    const int g     = lane >> 4;
    const int l     = lane & 15;
    const int split = sg * 4 + w;      // 0..31
    const int b     = pair >> 3;
    const int kv    = pair & 7;

    // q fragments (named), pre-scaled by (1/sqrt(128)) * log2(e)
    const float SCL = 0.08838834764831845f * 1.4426950408889634f;
    const float* qb = q + (size_t)b * HIDDEN + kv * 512 + l * 8;
    f4v q0a = *(const f4v*)(qb);         f4v q0b = *(const f4v*)(qb + 4);
    f4v q1a = *(const f4v*)(qb + 128);   f4v q1b = *(const f4v*)(qb + 132);
    f4v q2a = *(const f4v*)(qb + 256);   f4v q2b = *(const f4v*)(qb + 260);
    f4v q3a = *(const f4v*)(qb + 384);   f4v q3b = *(const f4v*)(qb + 388);
    q0a *= SCL; q0b *= SCL; q1a *= SCL; q1b *= SCL;
    q2a *= SCL; q2b *= SCL; q3a *= SCL; q3b *= SCL;

    const size_t base = (size_t)(b * N_KV + kv) * CACHE * HEAD_DIM;
    const int s0 = split * 128 + g;               // keys s0 + 4*it
    const float* kp = kc + base + (size_t)s0 * HEAD_DIM + l * 8;
    const float* vp = vc + base + (size_t)s0 * HEAD_DIM + l * 8;

    // named accumulators — stay in VGPRs (no runtime-indexed arrays)
    f4v o0a = 0.f, o0b = 0.f, o1a = 0.f, o1b = 0.f;
    f4v o2a = 0.f, o2b = 0.f, o3a = 0.f, o3b = 0.f;
    f4v lacv = 0.f;

    // preload iter 0 (K and V), nontemporal (single-use stream)
    f4v ka  = __builtin_nontemporal_load((const f4v*)kp);
    f4v kb4 = __builtin_nontemporal_load((const f4v*)(kp + 4));
    f4v va  = __builtin_nontemporal_load((const f4v*)vp);
    f4v vb4 = __builtin_nontemporal_load((const f4v*)(vp + 4));

    for (int it = 0; it < 32; ++it) {
        const int adv = (it < 31) ? 512 : 0;
        const float* kn = kp + adv;
        const float* vn = vp + adv;
        f4v kna = __builtin_nontemporal_load((const f4v*)kn);
        f4v knb = __builtin_nontemporal_load((const f4v*)(kn + 4));
        f4v vna = __builtin_nontemporal_load((const f4v*)vn);
        f4v vnb = __builtin_nontemporal_load((const f4v*)(vn + 4));

        float part0, part1, part2, part3;
        DOT8(part0, q0a, q0b)
        DOT8(part1, q1a, q1b)
        DOT8(part2, q2a, q2b)
        DOT8(part3, q3a, q3b)

        RED4(1) RED4(2) RED4(4) RED4(8)

        float pr0 = __builtin_amdgcn_exp2f(part0);
        float pr1 = __builtin_amdgcn_exp2f(part1);
        float pr2 = __builtin_amdgcn_exp2f(part2);
        float pr3 = __builtin_amdgcn_exp2f(part3);
        lacv.x += pr0; lacv.y += pr1; lacv.z += pr2; lacv.w += pr3;

        PVROW(pr0, o0a, o0b)
        PVROW(pr1, o1a, o1b)
        PVROW(pr2, o2a, o2b)
        PVROW(pr3, o3a, o3b)

        ka = kna; kb4 = knb;
        va = vna; vb4 = vnb;
        kp += 512; vp += 512;
    }

    // combine the 4 key-groups (lanes xor 16, 32)
    REDV(o0a, 16) REDV(o0b, 16) REDV(o1a, 16) REDV(o1b, 16)
    REDV(o2a, 16) REDV(o2b, 16) REDV(o3a, 16) REDV(o3b, 16)
    REDV(lacv, 16)
    REDV(o0a, 32) REDV(o0b, 32) REDV(o1a, 32) REDV(o1b, 32)
    REDV(o2a, 32) REDV(o2b, 32) REDV(o3a, 32) REDV(o3b, 32)
    REDV(lacv, 32)

    // lane (g,l) writes the r=g slice — branchless select, no array index
    f4v wa = (g & 2) ? ((g & 1) ? o3a : o2a) : ((g & 1) ? o1a : o0a);
    f4v wb = (g & 2) ? ((g & 1) ? o3b : o2b) : ((g & 1) ? o1b : o0b);
    float lsel = (g & 2) ? ((g & 1) ? lacv.w : lacv.z)
                         : ((g & 1) ? lacv.y : lacv.x);

    float* pod = po + ((((size_t)pair * 32 + split) * 4 + g) * 128) + l * 8;
    *(f4v*)pod       = wa;
    *(f4v*)(pod + 4) = wb;
    if (l == 0) pl[((size_t)pair * 32 + split) * 4 + g] = lsel;
}

// Sum 32 split partials, divide, add v_new. 512 blocks x 256 threads.
__global__ __launch_bounds__(256) void combine_attn(
    const float* __restrict__ po, const float* __restrict__ pl,
    const float* __restrict__ vnew, float* __restrict__ attnc)
{
    const int t    = blockIdx.x * 256 + threadIdx.x;  // 0..131071
    const int pair = t >> 9;
    const int rem  = t & 511;
    const int r    = rem >> 7;
    const int d    = rem & 127;
    const int b    = pair >> 3;
    const int kv   = pair & 7;

    float os = 0.f, ls = 0.f;
#pragma unroll 4
    for (int s = 0; s < 32; ++s) {
        os += po[(((size_t)pair * 32 + s) * 4 + r) * 128 + d];
        ls += pl[((size_t)pair * 32 + s) * 4 + r];
    }
    float val = os / ls + vnew[(size_t)b * (N_KV * HEAD_DIM) + kv * 128 + d];
    attnc[(size_t)b * HIDDEN + kv * 512 + r * 128 + d] = val;
}

// ---------------------------------------------------------------------------
extern "C" void kernel_launch(void* const* d_in, const int* in_sizes, int n_in,
                              void* d_out, int out_size, void* d_ws, size_t ws_size,
                              hipStream_t stream)
{
    const float* x   = (const float*)d_in[0];
    const float* kc  = (const float*)d_in[1];
    const float* vc  = (const float*)d_in[2];
    const float* wq  = (const float*)d_in[3];
    // d_in[4] = wk : dead in the reference (k_new never used) — skipped.
    const float* wv  = (const float*)d_in[5];
    const float* wo  = (const float*)d_in[6];
    float* out = (float*)d_out;

    // workspace layout (floats) — scratch region S reused serially:
    //   pA (proj1 partials, 5.24M) -> po+pl (attn partials, 4.23M) -> pC (4.19M)
    float* ws    = (float*)d_ws;
    float* q     = ws;                    // 131072
    float* vnew  = ws + 131072;           // 32768
    float* attnc = ws + 163840;           // 131072
    float* S     = ws + 294912;
    float* pA    = S;                     // 32*32*5120 = 5242880
    float* po    = S;                     // 256*32*4*128 = 4194304 (after pA dead)
    float* pl    = S + 4194304;           // 32768
    float* pC    = S;                     // 32*32*4096 = 4194304 (after po dead)

    // 1) q = x@wq, v_new = x@wv (fused, 5120 columns)
    proj_kernel<<<dim3(20, 32), PJ_THREADS, 0, stream>>>(x, wq, 4096, 4096, wv, 1024, pA, 5120);
    combine_proj<<<dim3(20, 32), 256, 0, stream>>>(pA, 5120, q, 4096, 4096, vnew, 1024);

    // 2) attention over KV cache
    // MEASUREMENT ROUND: attn_kernel launched 3x (identical dispatches writing
    // identical deterministic values — WAW of equal data on a serial stream).
    //   attn_dur = (dur_R5 - dur_R4) / 2
    attn_kernel<<<2048, 256, 0, stream>>>(q, kc, vc, po, pl);
    attn_kernel<<<2048, 256, 0, stream>>>(q, kc, vc, po, pl);
    attn_kernel<<<2048, 256, 0, stream>>>(q, kc, vc, po, pl);
    combine_attn<<<512, 256, 0, stream>>>(po, pl, vnew, attnc);

    // 3) out = attn @ wo
    proj_kernel<<<dim3(16, 32), PJ_THREADS, 0, stream>>>(attnc, wo, 4096, 4096, wo, 4096, pC, 4096);
    combine_proj<<<dim3(16, 32), 256, 0, stream>>>(pC, 4096, out, 4096, 4096, out, 4096);
}

// Round 6
// 293.528 us; speedup vs baseline: 2.4917x; 2.4917x over previous
//
#include <hip/hip_runtime.h>
#include <hip/hip_bf16.h>

// Problem constants
#define HIDDEN   4096
#define N_HEADS  32
#define N_KV     8
#define N_REP    4
#define HEAD_DIM 128
#define CACHE    4096
#define BATCH    32

#define PJ_THREADS 128
#define PJ_COLS    256     // columns per block (2 per thread)
#define PJ_HCHUNK  128     // K-chunk per block (grid.y = 4096/128 = 32)

typedef float f4v __attribute__((ext_vector_type(4)));

// ---------------------------------------------------------------------------
// Skinny GEMM: part[hc][b][col] = sum_{h in chunk} X[b][h] * W[h][col], M=32.
// 8-row weight batches, peeled depth-1 prefetch (~1024 cy cover vs ~900 cy
// HBM latency at ~1.25 waves/SIMD).
// ---------------------------------------------------------------------------
__global__ __launch_bounds__(128) void proj_kernel(
    const float* __restrict__ X,           // [32][4096]
    const float* __restrict__ W1, int ld1, int ncol1,
    const float* __restrict__ W2, int ld2,
    float* __restrict__ part, int ncols)
{
    __shared__ float xs[32 * PJ_HCHUNK];   // 16 KB
    const int hc   = blockIdx.y;           // 0..31
    const int h0   = hc * PJ_HCHUNK;
    const int col0 = blockIdx.x * PJ_COLS;
    const int tid  = threadIdx.x;

    for (int i = tid * 4; i < 32 * PJ_HCHUNK; i += PJ_THREADS * 4) {
        int b = i >> 7, j = i & 127;
        *(float4*)&xs[i] = *(const float4*)&X[(size_t)b * HIDDEN + h0 + j];
    }
    __syncthreads();

    const int col = col0 + tid * 2;
    const float* Wp;
    size_t ld;
    if (col < ncol1) { Wp = W1 + (size_t)h0 * ld1 + col;           ld = ld1; }
    else             { Wp = W2 + (size_t)h0 * ld2 + (col - ncol1); ld = ld2; }

    float2 acc[32];
#pragma unroll
    for (int b = 0; b < 32; ++b) acc[b] = make_float2(0.f, 0.f);

    float2 wc[8], wn[8];
#pragma unroll
    for (int r = 0; r < 8; ++r) wc[r] = *(const float2*)(Wp + r * ld);
    Wp += 8 * ld;

#define PJ_COMPUTE(XR)                                                  \
    _Pragma("unroll")                                                   \
    for (int b = 0; b < 32; ++b) {                                      \
        float4 x0 = *(const float4*)((XR) + b * PJ_HCHUNK);             \
        float4 x1 = *(const float4*)((XR) + b * PJ_HCHUNK + 4);         \
        acc[b].x = fmaf(x0.x, wc[0].x, acc[b].x);                       \
        acc[b].y = fmaf(x0.x, wc[0].y, acc[b].y);                       \
        acc[b].x = fmaf(x0.y, wc[1].x, acc[b].x);                       \
        acc[b].y = fmaf(x0.y, wc[1].y, acc[b].y);                       \
        acc[b].x = fmaf(x0.z, wc[2].x, acc[b].x);                       \
        acc[b].y = fmaf(x0.z, wc[2].y, acc[b].y);                       \
        acc[b].x = fmaf(x0.w, wc[3].x, acc[b].x);                       \
        acc[b].y = fmaf(x0.w, wc[3].y, acc[b].y);                       \
        acc[b].x = fmaf(x1.x, wc[4].x, acc[b].x);                       \
        acc[b].y = fmaf(x1.x, wc[4].y, acc[b].y);                       \
        acc[b].x = fmaf(x1.y, wc[5].x, acc[b].x);                       \
        acc[b].y = fmaf(x1.y, wc[5].y, acc[b].y);                       \
        acc[b].x = fmaf(x1.z, wc[6].x, acc[b].x);                       \
        acc[b].y = fmaf(x1.z, wc[6].y, acc[b].y);                       \
        acc[b].x = fmaf(x1.w, wc[7].x, acc[b].x);                       \
        acc[b].y = fmaf(x1.w, wc[7].y, acc[b].y);                       \
    }

    for (int bt = 0; bt < (PJ_HCHUNK / 8) - 1; ++bt) {
#pragma unroll
        for (int r = 0; r < 8; ++r) wn[r] = *(const float2*)(Wp + r * ld);
        const float* xr = xs + bt * 8;
        PJ_COMPUTE(xr)
#pragma unroll
        for (int r = 0; r < 8; ++r) wc[r] = wn[r];
        Wp += 8 * ld;
    }
    {
        const float* xr = xs + PJ_HCHUNK - 8;
        PJ_COMPUTE(xr)
    }
#undef PJ_COMPUTE

    float* dst = part + ((size_t)hc * 32) * ncols + col;
#pragma unroll
    for (int b = 0; b < 32; ++b)
        *(float2*)(dst + (size_t)b * ncols) = acc[b];
}

// Sum 32 h-chunk partials. grid = (ncols/256, 32)
__global__ __launch_bounds__(256) void combine_proj(
    const float* __restrict__ part, int ncols,
    float* __restrict__ dst1, int ld1, int ncol1,
    float* __restrict__ dst2, int ld2)
{
    const int col = blockIdx.x * 256 + threadIdx.x;
    const int b   = blockIdx.y;
    float s = 0.f;
#pragma unroll
    for (int i = 0; i < 32; ++i) s += part[((size_t)i * 32 + b) * ncols + col];
    if (col < ncol1) dst1[(size_t)b * ld1 + col] = s;
    else             dst2[(size_t)b * ld2 + (col - ncol1)] = s;
}

// ---------------------------------------------------------------------------
// Decode attention. Score reduce over the 16-lane row now uses DPP row_ror
// adds on the VALU pipe (v_add_f32 dpp) instead of 16 ds_swizzle ops/iter —
// frees the LDS pipe, which was co-limiting the KV stream at ~21 B/cy/CU.
// ---------------------------------------------------------------------------

template<int CTRL>
__device__ __forceinline__ float dpp_ror(float x) {
    return __int_as_float(__builtin_amdgcn_update_dpp(
        0, __float_as_int(x), CTRL, 0xF, 0xF, true));
}

#define DOT8(PART, QA, QB)                         \
    PART = QA.x * ka.x;                            \
    PART = fmaf(QA.y, ka.y, PART);                 \
    PART = fmaf(QA.z, ka.z, PART);                 \
    PART = fmaf(QA.w, ka.w, PART);                 \
    PART = fmaf(QB.x, kb4.x, PART);                \
    PART = fmaf(QB.y, kb4.y, PART);                \
    PART = fmaf(QB.z, kb4.z, PART);                \
    PART = fmaf(QB.w, kb4.w, PART);

// row_ror:n = 0x120 + n ; rotate-reduce within each 16-lane row
#define RED4_DPP(CTRL)                             \
    part0 += dpp_ror<CTRL>(part0);                 \
    part1 += dpp_ror<CTRL>(part1);                 \
    part2 += dpp_ror<CTRL>(part2);                 \
    part3 += dpp_ror<CTRL>(part3);

#define PVROW(PR, OA, OB)                          \
    OA.x = fmaf(PR, va.x,  OA.x);                  \
    OA.y = fmaf(PR, va.y,  OA.y);                  \
    OA.z = fmaf(PR, va.z,  OA.z);                  \
    OA.w = fmaf(PR, va.w,  OA.w);                  \
    OB.x = fmaf(PR, vb4.x, OB.x);                  \
    OB.y = fmaf(PR, vb4.y, OB.y);                  \
    OB.z = fmaf(PR, vb4.z, OB.z);                  \
    OB.w = fmaf(PR, vb4.w, OB.w);

#define REDV(V, M)                                 \
    V.x += __shfl_xor(V.x, M, 64);                 \
    V.y += __shfl_xor(V.y, M, 64);                 \
    V.z += __shfl_xor(V.z, M, 64);                 \
    V.w += __shfl_xor(V.w, M, 64);

__global__ __launch_bounds__(256, 4) void attn_kernel(
    const float* __restrict__ q,      // [32][4096], col = (kv*4+r)*128+d
    const float* __restrict__ kc,     // [32][8][4096][128]
    const float* __restrict__ vc,
    float* __restrict__ po,
    float* __restrict__ pl)
{
    const int bid   = blockIdx.x;      // 0..2047
    const int pair  = bid >> 3;        // 0..255
    const int sg    = bid & 7;
    const int tid   = threadIdx.x;
    const int w     = tid >> 6;
    const int lane  = tid & 63;
    const int g     = lane >> 4;
    const int l     = lane & 15;
    const int split = sg * 4 + w;      // 0..31
    const int b     = pair >> 3;
    const int kv    = pair & 7;

    // q fragments (named), pre-scaled by (1/sqrt(128)) * log2(e)
    const float SCL = 0.08838834764831845f * 1.4426950408889634f;
    const float* qb = q + (size_t)b * HIDDEN + kv * 512 + l * 8;
    f4v q0a = *(const f4v*)(qb);         f4v q0b = *(const f4v*)(qb + 4);
    f4v q1a = *(const f4v*)(qb + 128);   f4v q1b = *(const f4v*)(qb + 132);
    f4v q2a = *(const f4v*)(qb + 256);   f4v q2b = *(const f4v*)(qb + 260);
    f4v q3a = *(const f4v*)(qb + 384);   f4v q3b = *(const f4v*)(qb + 388);
    q0a *= SCL; q0b *= SCL; q1a *= SCL; q1b *= SCL;
    q2a *= SCL; q2b *= SCL; q3a *= SCL; q3b *= SCL;

    const size_t base = (size_t)(b * N_KV + kv) * CACHE * HEAD_DIM;
    const int s0 = split * 128 + g;               // keys s0 + 4*it
    const float* kp = kc + base + (size_t)s0 * HEAD_DIM + l * 8;
    const float* vp = vc + base + (size_t)s0 * HEAD_DIM + l * 8;

    // named accumulators — stay in VGPRs (no runtime-indexed arrays)
    f4v o0a = 0.f, o0b = 0.f, o1a = 0.f, o1b = 0.f;
    f4v o2a = 0.f, o2b = 0.f, o3a = 0.f, o3b = 0.f;
    f4v lacv = 0.f;

    // preload iter 0 (K and V), nontemporal (single-use stream)
    f4v ka  = __builtin_nontemporal_load((const f4v*)kp);
    f4v kb4 = __builtin_nontemporal_load((const f4v*)(kp + 4));
    f4v va  = __builtin_nontemporal_load((const f4v*)vp);
    f4v vb4 = __builtin_nontemporal_load((const f4v*)(vp + 4));

    for (int it = 0; it < 32; ++it) {
        const int adv = (it < 31) ? 512 : 0;
        const float* kn = kp + adv;
        const float* vn = vp + adv;
        f4v kna = __builtin_nontemporal_load((const f4v*)kn);
        f4v knb = __builtin_nontemporal_load((const f4v*)(kn + 4));
        f4v vna = __builtin_nontemporal_load((const f4v*)vn);
        f4v vnb = __builtin_nontemporal_load((const f4v*)(vn + 4));

        float part0, part1, part2, part3;
        DOT8(part0, q0a, q0b)
        DOT8(part1, q1a, q1b)
        DOT8(part2, q2a, q2b)
        DOT8(part3, q3a, q3b)

        // rotate-reduce across the 16-lane row on the VALU pipe
        RED4_DPP(0x121)   // row_ror:1
        RED4_DPP(0x122)   // row_ror:2
        RED4_DPP(0x124)   // row_ror:4
        RED4_DPP(0x128)   // row_ror:8

        float pr0 = __builtin_amdgcn_exp2f(part0);
        float pr1 = __builtin_amdgcn_exp2f(part1);
        float pr2 = __builtin_amdgcn_exp2f(part2);
        float pr3 = __builtin_amdgcn_exp2f(part3);
        lacv.x += pr0; lacv.y += pr1; lacv.z += pr2; lacv.w += pr3;

        PVROW(pr0, o0a, o0b)
        PVROW(pr1, o1a, o1b)
        PVROW(pr2, o2a, o2b)
        PVROW(pr3, o3a, o3b)

        ka = kna; kb4 = knb;
        va = vna; vb4 = vnb;
        kp += 512; vp += 512;
    }

    // combine the 4 key-groups (lanes xor 16, 32) — epilogue, amortized
    REDV(o0a, 16) REDV(o0b, 16) REDV(o1a, 16) REDV(o1b, 16)
    REDV(o2a, 16) REDV(o2b, 16) REDV(o3a, 16) REDV(o3b, 16)
    REDV(lacv, 16)
    REDV(o0a, 32) REDV(o0b, 32) REDV(o1a, 32) REDV(o1b, 32)
    REDV(o2a, 32) REDV(o2b, 32) REDV(o3a, 32) REDV(o3b, 32)
    REDV(lacv, 32)

    // lane (g,l) writes the r=g slice — branchless select, no array index
    f4v wa = (g & 2) ? ((g & 1) ? o3a : o2a) : ((g & 1) ? o1a : o0a);
    f4v wb = (g & 2) ? ((g & 1) ? o3b : o2b) : ((g & 1) ? o1b : o0b);
    float lsel = (g & 2) ? ((g & 1) ? lacv.w : lacv.z)
                         : ((g & 1) ? lacv.y : lacv.x);

    float* pod = po + ((((size_t)pair * 32 + split) * 4 + g) * 128) + l * 8;
    *(f4v*)pod       = wa;
    *(f4v*)(pod + 4) = wb;
    if (l == 0) pl[((size_t)pair * 32 + split) * 4 + g] = lsel;
}

// Sum 32 split partials, divide, add v_new. 512 blocks x 256 threads.
__global__ __launch_bounds__(256) void combine_attn(
    const float* __restrict__ po, const float* __restrict__ pl,
    const float* __restrict__ vnew, float* __restrict__ attnc)
{
    const int t    = blockIdx.x * 256 + threadIdx.x;  // 0..131071
    const int pair = t >> 9;
    const int rem  = t & 511;
    const int r    = rem >> 7;
    const int d    = rem & 127;
    const int b    = pair >> 3;
    const int kv   = pair & 7;

    float os = 0.f, ls = 0.f;
#pragma unroll 4
    for (int s = 0; s < 32; ++s) {
        os += po[(((size_t)pair * 32 + s) * 4 + r) * 128 + d];
        ls += pl[((size_t)pair * 32 + s) * 4 + r];
    }
    float val = os / ls + vnew[(size_t)b * (N_KV * HEAD_DIM) + kv * 128 + d];
    attnc[(size_t)b * HIDDEN + kv * 512 + r * 128 + d] = val;
}

// ---------------------------------------------------------------------------
extern "C" void kernel_launch(void* const* d_in, const int* in_sizes, int n_in,
                              void* d_out, int out_size, void* d_ws, size_t ws_size,
                              hipStream_t stream)
{
    const float* x   = (const float*)d_in[0];
    const float* kc  = (const float*)d_in[1];
    const float* vc  = (const float*)d_in[2];
    const float* wq  = (const float*)d_in[3];
    // d_in[4] = wk : dead in the reference (k_new never used) — skipped.
    const float* wv  = (const float*)d_in[5];
    const float* wo  = (const float*)d_in[6];
    float* out = (float*)d_out;

    // workspace layout (floats) — scratch region S reused serially:
    //   pA (proj1 partials, 5.24M) -> po+pl (attn partials, 4.23M) -> pC (4.19M)
    float* ws    = (float*)d_ws;
    float* q     = ws;                    // 131072
    float* vnew  = ws + 131072;           // 32768
    float* attnc = ws + 163840;           // 131072
    float* S     = ws + 294912;
    float* pA    = S;                     // 32*32*5120 = 5242880
    float* po    = S;                     // 256*32*4*128 = 4194304 (after pA dead)
    float* pl    = S + 4194304;           // 32768
    float* pC    = S;                     // 32*32*4096 = 4194304 (after po dead)

    // 1) q = x@wq, v_new = x@wv (fused, 5120 columns)
    proj_kernel<<<dim3(20, 32), PJ_THREADS, 0, stream>>>(x, wq, 4096, 4096, wv, 1024, pA, 5120);
    combine_proj<<<dim3(20, 32), 256, 0, stream>>>(pA, 5120, q, 4096, 4096, vnew, 1024);

    // 2) attention over KV cache
    attn_kernel<<<2048, 256, 0, stream>>>(q, kc, vc, po, pl);
    combine_attn<<<512, 256, 0, stream>>>(po, pl, vnew, attnc);

    // 3) out = attn @ wo
    proj_kernel<<<dim3(16, 32), PJ_THREADS, 0, stream>>>(attnc, wo, 4096, 4096, wo, 4096, pC, 4096);
    combine_proj<<<dim3(16, 32), 256, 0, stream>>>(pC, 4096, out, 4096, 4096, out, 4096);
}